// Round 7
// baseline (59.187 us; speedup 1.0000x reference)
//
#include <hip/hip_runtime.h>
#include <math.h>

// B=128, N=512, D=1024, C=512
// s: (128,1536) f32, a=s[:,:512], z=s[:,512:]; out: (128,1536) f32 = [da | dz]
// GEMM1: da = tanh([a|ctx](128x1024) @ [Wa;Wc](1024x512) + ba)
// GEMM2: c  = a(128x512) @ Wl(512x1024) + bl          -> ws
// dz[b,i] = sum_k c[b,k] * z[b,(i+k)%1024]
//
// SINGLE kernel, 256 blocks x 512 threads (all co-resident: 1 block/CU), plus
// a tiny memset node zeroing 2 flag ints each call (replay-safe).
//   blocks 0..127 : GEMM1 job (32 rows x 16 cols, 8 waves = 2 M x 4 K-quarter)
//   blocks 128..191: GEMM2 job mt=0 (64 rows x 16 cols, 4 M x 2 K-half)
//   blocks 192..255: GEMM2 job mt=1
// GEMM2 blocks release c via __threadfence() + atomicAdd(flag[mt]).
// Then every block runs one dz job (b=bid>>1, ih=bid&1), spin-waiting on
// flag[b>>6]==64 (acquire) before reading c. Cross-assignment: consumers of
// flag0 (bids 0..127) are not its producers (128..191) -> no self-stall;
// group 192..255 self-signals before waiting (safe, unconditional).
//
// GEMM fragment code and dz code are the round-5/6-validated bodies.
// Fragment k-slot bijection sigma(kq,j): j<4 -> 4kq+j ; j>=4 -> 16+4kq+(j-4),
// applied identically to A and B (validated rounds 2-6).

typedef float f32x4 __attribute__((ext_vector_type(4)));
typedef __bf16 bf16x8 __attribute__((ext_vector_type(8)));

#define FLAG_OFF_BYTES 524288   // after c (128*1024*4B)

__device__ __forceinline__ bf16x8 pack2(float4 v0, float4 v1) {
    bf16x8 r;
    r[0] = (__bf16)v0.x; r[1] = (__bf16)v0.y; r[2] = (__bf16)v0.z; r[3] = (__bf16)v0.w;
    r[4] = (__bf16)v1.x; r[5] = (__bf16)v1.y; r[6] = (__bf16)v1.z; r[7] = (__bf16)v1.w;
    return r;
}

__device__ __forceinline__ f32x4 MFMA(bf16x8 a, uint4 b, f32x4 c) {
    return __builtin_amdgcn_mfma_f32_16x16x32_bf16(a, __builtin_bit_cast(bf16x8, b), c, 0, 0, 0);
}

__global__ __launch_bounds__(512) void k_all(
    const float* __restrict__ s, const float* __restrict__ ctx,
    const float* __restrict__ Wa, const float* __restrict__ Wc,
    const float* __restrict__ ba, const float* __restrict__ Wl,
    const float* __restrict__ bl, float* out,
    float* cws, int* flags)
{
    // GEMM: Bg frags [<=32 ks][64 l][8 bf16] = 32 KB @0 ; red f32 @32768 (7.5KB)
    // dz:   zdup 2064 f @0 ; part 8*512 f @8448
    __shared__ __align__(16) unsigned char smem[40448];

    const int bid = blockIdx.x;
    const int t = threadIdx.x;
    const int w = t >> 6, l = t & 63;
    const int lk = l & 15, kq = l >> 4;

    unsigned short* Bg = reinterpret_cast<unsigned short*>(smem);
    float* red = reinterpret_cast<float*>(smem + 32768);

    if (bid < 128) {
        // ---------------- GEMM1: 32 rows x 16 cols, KS=32, 2M x 4Kq waves
        const int mt = bid >> 5, nt = bid & 31;
        const int col = nt * 16 + lk;

        #pragma unroll 4
        for (int i = 0; i < 4; ++i) {                 // stage 4 ks per wave
            const int ks = w * 4 + i;
            const int kb = ks * 32;
            const float* wb; int krel;
            if (ks < 16) { wb = Wa; krel = kb; } else { wb = Wc; krel = kb - 512; }
            bf16x8 fr;
            #pragma unroll
            for (int jj = 0; jj < 4; ++jj)
                fr[jj] = (__bf16)wb[(size_t)(krel + 4 * kq + jj) * 512 + col];
            #pragma unroll
            for (int jj = 0; jj < 4; ++jj)
                fr[4 + jj] = (__bf16)wb[(size_t)(krel + 16 + 4 * kq + jj) * 512 + col];
            *reinterpret_cast<uint4*>(&Bg[(ks * 64 + l) * 8]) = __builtin_bit_cast(uint4, fr);
        }
        __syncthreads();

        const int wm = w & 1, wk = w >> 1;            // M-frag, K-quarter
        const int R0 = mt * 32 + wm * 16;
        const float* srow = s + (size_t)(R0 + lk) * 1536;
        const float* crow = ctx + (size_t)(R0 + lk) * 512;
        f32x4 acc0 = (f32x4){0.f, 0.f, 0.f, 0.f};
        f32x4 acc1 = (f32x4){0.f, 0.f, 0.f, 0.f};
        #pragma unroll 4
        for (int i = 0; i < 8; ++i) {
            const int ks = wk * 8 + i;
            const int kb = ks * 32;
            float4 v0, v1;
            if (ks >= 16) {
                v0 = *reinterpret_cast<const float4*>(crow + (kb - 512) + 4 * kq);
                v1 = *reinterpret_cast<const float4*>(crow + (kb - 512) + 16 + 4 * kq);
            } else {
                v0 = *reinterpret_cast<const float4*>(srow + kb + 4 * kq);
                v1 = *reinterpret_cast<const float4*>(srow + kb + 16 + 4 * kq);
            }
            bf16x8 af = pack2(v0, v1);
            uint4 bv = *reinterpret_cast<const uint4*>(&Bg[(ks * 64 + l) * 8]);
            if (i & 1) acc1 = MFMA(af, bv, acc1);
            else       acc0 = MFMA(af, bv, acc0);
        }
        f32x4 sum = acc0 + acc1;

        if (wk > 0) {                                  // 4-way K reduce
            #pragma unroll
            for (int r = 0; r < 4; ++r)
                red[((wk - 1) * 32 + wm * 16 + 4 * kq + r) * 20 + lk] = sum[r];
        }
        __syncthreads();
        if (wk == 0) {
            const float bias = ba[col];
            #pragma unroll
            for (int r = 0; r < 4; ++r) {
                const int m = wm * 16 + 4 * kq + r;
                float v = sum[r] + red[m * 20 + lk] + red[(32 + m) * 20 + lk]
                        + red[(64 + m) * 20 + lk] + bias;
                out[(size_t)(R0 + 4 * kq + r) * 1536 + col] = tanhf(v);
            }
        }
    } else {
        // ---------------- GEMM2: 64 rows x 16 cols, KS=16, 4M x 2Kh waves
        const int mt = (bid >= 192) ? 1 : 0;
        const int nt = bid - 128 - mt * 64;
        const int col = nt * 16 + lk;

        #pragma unroll 2
        for (int i = 0; i < 2; ++i) {                 // stage 2 ks per wave
            const int ks = w * 2 + i;
            const int kb = ks * 32;
            bf16x8 fr;
            #pragma unroll
            for (int jj = 0; jj < 4; ++jj)
                fr[jj] = (__bf16)Wl[(size_t)(kb + 4 * kq + jj) * 1024 + col];
            #pragma unroll
            for (int jj = 0; jj < 4; ++jj)
                fr[4 + jj] = (__bf16)Wl[(size_t)(kb + 16 + 4 * kq + jj) * 1024 + col];
            *reinterpret_cast<uint4*>(&Bg[(ks * 64 + l) * 8]) = __builtin_bit_cast(uint4, fr);
        }
        __syncthreads();

        const int wm = w & 3, wk = w >> 2;            // M-frag, K-half
        const int R0 = mt * 64 + wm * 16;
        const float* srow = s + (size_t)(R0 + lk) * 1536;
        f32x4 acc0 = (f32x4){0.f, 0.f, 0.f, 0.f};
        f32x4 acc1 = (f32x4){0.f, 0.f, 0.f, 0.f};
        #pragma unroll 4
        for (int i = 0; i < 8; ++i) {
            const int ks = wk * 8 + i;
            const int kb = ks * 32;
            float4 v0 = *reinterpret_cast<const float4*>(srow + kb + 4 * kq);
            float4 v1 = *reinterpret_cast<const float4*>(srow + kb + 16 + 4 * kq);
            bf16x8 af = pack2(v0, v1);
            uint4 bv = *reinterpret_cast<const uint4*>(&Bg[(ks * 64 + l) * 8]);
            if (i & 1) acc1 = MFMA(af, bv, acc1);
            else       acc0 = MFMA(af, bv, acc0);
        }
        f32x4 sum = acc0 + acc1;

        if (wk == 1) {                                 // pair K reduce
            #pragma unroll
            for (int r = 0; r < 4; ++r)
                red[(wm * 16 + 4 * kq + r) * 20 + lk] = sum[r];
        }
        __syncthreads();
        if (wk == 0) {
            const float bias = bl[col];
            #pragma unroll
            for (int r = 0; r < 4; ++r) {
                float v = sum[r] + red[(wm * 16 + 4 * kq + r) * 20 + lk] + bias;
                cws[(size_t)(R0 + 4 * kq + r) * 1024 + col] = v;
            }
        }
        // ---- release c: all stores drained at barrier (same CU/XCD L2),
        //      t0 fence writes back L2, then device-scope signal.
        __syncthreads();
        if (t == 0) {
            __threadfence();
            atomicAdd(flags + mt, 1);
        }
    }

    // ======================= dz phase (all 256 blocks) =======================
    __syncthreads();                                   // smem reuse safety
    {
        float* zdup = reinterpret_cast<float*>(smem);             // 2064 f
        float* part = reinterpret_cast<float*>(smem + 8448);      // 8*512 f
        const int b = bid >> 1;
        const int ih = bid & 1;

        if (t < 256) {                                 // z staging (no c dep)
            float4 v = reinterpret_cast<const float4*>(s + (size_t)b * 1536 + 512)[t];
            reinterpret_cast<float4*>(zdup)[t] = v;
            reinterpret_cast<float4*>(zdup)[256 + t] = v;
        }
        __syncthreads();

        if (t == 0) {                                  // acquire c[b,:]
            const int mtc = b >> 6;
            while (__hip_atomic_load(flags + mtc, __ATOMIC_ACQUIRE,
                                     __HIP_MEMORY_SCOPE_AGENT) < 64)
                __builtin_amdgcn_s_sleep(8);
        }
        __syncthreads();
        __threadfence();                               // invalidate stale L1/L2

        const int g = t & 63;
        const int kq2 = __builtin_amdgcn_readfirstlane(t >> 6);
        const float4* c4 = reinterpret_cast<const float4*>(cws + (size_t)b * 1024 + kq2 * 128);
        const int I0 = ih * 512;
        const float4* z4 = reinterpret_cast<const float4*>(zdup);
        const int baseA = (I0 >> 2) + g + kq2 * 32;
        const int baseB = baseA + 64;
        float4 a0 = z4[baseA], a1 = z4[baseA + 1];
        float4 b0 = z4[baseB], b1 = z4[baseB + 1];
        float accA[4] = {0.f, 0.f, 0.f, 0.f}, accB[4] = {0.f, 0.f, 0.f, 0.f};
        #pragma unroll 4
        for (int m = 0; m < 32; ++m) {
            float4 cv = c4[m];
            float4 a2 = z4[baseA + m + 2];
            float4 b2 = z4[baseB + m + 2];
            accA[0] = fmaf(cv.x, a0.x, accA[0]); accA[0] = fmaf(cv.y, a0.y, accA[0]);
            accA[0] = fmaf(cv.z, a0.z, accA[0]); accA[0] = fmaf(cv.w, a0.w, accA[0]);
            accA[1] = fmaf(cv.x, a0.y, accA[1]); accA[1] = fmaf(cv.y, a0.z, accA[1]);
            accA[1] = fmaf(cv.z, a0.w, accA[1]); accA[1] = fmaf(cv.w, a1.x, accA[1]);
            accA[2] = fmaf(cv.x, a0.z, accA[2]); accA[2] = fmaf(cv.y, a0.w, accA[2]);
            accA[2] = fmaf(cv.z, a1.x, accA[2]); accA[2] = fmaf(cv.w, a1.y, accA[2]);
            accA[3] = fmaf(cv.x, a0.w, accA[3]); accA[3] = fmaf(cv.y, a1.x, accA[3]);
            accA[3] = fmaf(cv.z, a1.y, accA[3]); accA[3] = fmaf(cv.w, a1.z, accA[3]);
            accB[0] = fmaf(cv.x, b0.x, accB[0]); accB[0] = fmaf(cv.y, b0.y, accB[0]);
            accB[0] = fmaf(cv.z, b0.z, accB[0]); accB[0] = fmaf(cv.w, b0.w, accB[0]);
            accB[1] = fmaf(cv.x, b0.y, accB[1]); accB[1] = fmaf(cv.y, b0.z, accB[1]);
            accB[1] = fmaf(cv.z, b0.w, accB[1]); accB[1] = fmaf(cv.w, b1.x, accB[1]);
            accB[2] = fmaf(cv.x, b0.z, accB[2]); accB[2] = fmaf(cv.y, b0.w, accB[2]);
            accB[2] = fmaf(cv.z, b1.x, accB[2]); accB[2] = fmaf(cv.w, b1.y, accB[2]);
            accB[3] = fmaf(cv.x, b0.w, accB[3]); accB[3] = fmaf(cv.y, b1.x, accB[3]);
            accB[3] = fmaf(cv.z, b1.y, accB[3]); accB[3] = fmaf(cv.w, b1.z, accB[3]);
            a0 = a1; a1 = a2; b0 = b1; b1 = b2;
        }
        *reinterpret_cast<float4*>(&part[kq2 * 512 + 4 * g]) =
            make_float4(accA[0], accA[1], accA[2], accA[3]);
        *reinterpret_cast<float4*>(&part[kq2 * 512 + 256 + 4 * g]) =
            make_float4(accB[0], accB[1], accB[2], accB[3]);
        __syncthreads();
        float sumz = 0.f;
        #pragma unroll
        for (int q = 0; q < 8; ++q) sumz += part[q * 512 + t];
        out[(size_t)b * 1536 + 512 + I0 + t] = sumz;
    }
}

extern "C" void kernel_launch(void* const* d_in, const int* in_sizes, int n_in,
                              void* d_out, int out_size, void* d_ws, size_t ws_size,
                              hipStream_t stream) {
    // inputs: 0=t, 1=s, 2=context, 3=Wa, 4=Wc, 5=ba, 6=Wl, 7=bl
    const float* s   = (const float*)d_in[1];
    const float* ctx = (const float*)d_in[2];
    const float* Wa  = (const float*)d_in[3];
    const float* Wc  = (const float*)d_in[4];
    const float* ba  = (const float*)d_in[5];
    const float* Wl  = (const float*)d_in[6];
    const float* bl  = (const float*)d_in[7];
    float* out = (float*)d_out;
    float* cws = (float*)d_ws;
    int* flags = (int*)((char*)d_ws + FLAG_OFF_BYTES);

    hipMemsetAsync(flags, 0, 2 * sizeof(int), stream);
    k_all<<<256, 512, 0, stream>>>(s, ctx, Wa, Wc, ba, Wl, bl, out, cws, flags);
}

// Round 8
// 15.962 us; speedup vs baseline: 3.7080x; 3.7080x over previous
//
#include <hip/hip_runtime.h>
#include <math.h>

// B=128, N=512, D=1024, C=512
// s: (128,1536) f32, a=s[:,:512], z=s[:,512:]; out: (128,1536) f32 = [da | dz]
// GEMM1: da = tanh([a|ctx](128x1024) @ [Wa;Wc](1024x512) + ba)
// GEMM2: c  = a(128x512) @ Wl(512x1024) + bl          -> ws
// dz[b,i] = sum_k c[b,k] * z[b,(i+k)%1024]
//
// Dependency-minimal split:
//   k1 (272 blocks): bid<256 -> GEMM2 job (32 rows x 16 cols, A staged
//       coalesced->LDS in fragment layout, B frags LDS, 2Mx4K waves, c->ws)
//       bid>=256 -> Apack ([a|ctx] -> bf16 fragments in ws)  [R4-validated]
//   k2 (512 blocks): bid<256 -> dz (batch,i-half)            [R3-validated]
//       bid>=256 -> GEMM1 job (16 rows x 16 cols, A streamed from Apack,
//       B frags LDS, 8-way K-split + LDS reduce, tanh)       [R3-validated]
//
// ws: Apack @0 (256 KB) ; c @262144 (512 KB)
// Fragment k-slot bijection sigma(kq,j): j<4 -> 4kq+j ; j>=4 -> 16+4kq+(j-4),
// applied identically to A and B (validated rounds 2-7).

typedef float f32x4 __attribute__((ext_vector_type(4)));
typedef __bf16 bf16x8 __attribute__((ext_vector_type(8)));
typedef __bf16 bf16x4 __attribute__((ext_vector_type(4)));

#define C_OFF_BYTES 262144

__device__ __forceinline__ bf16x8 pack2(float4 v0, float4 v1) {
    bf16x8 r;
    r[0] = (__bf16)v0.x; r[1] = (__bf16)v0.y; r[2] = (__bf16)v0.z; r[3] = (__bf16)v0.w;
    r[4] = (__bf16)v1.x; r[5] = (__bf16)v1.y; r[6] = (__bf16)v1.z; r[7] = (__bf16)v1.w;
    return r;
}

__device__ __forceinline__ uint2 cvt4(float4 v) {
    bf16x4 r;
    r[0] = (__bf16)v.x; r[1] = (__bf16)v.y; r[2] = (__bf16)v.z; r[3] = (__bf16)v.w;
    return __builtin_bit_cast(uint2, r);
}

__device__ __forceinline__ f32x4 MFMA(uint4 a, uint4 b, f32x4 c) {
    return __builtin_amdgcn_mfma_f32_16x16x32_bf16(
        __builtin_bit_cast(bf16x8, a), __builtin_bit_cast(bf16x8, b), c, 0, 0, 0);
}

// ---------------------------------------------------------------------------
// k1: 272 blocks x 512 threads.  [0,256): GEMM2 ; [256,272): Apack
// ---------------------------------------------------------------------------
__global__ __launch_bounds__(512) void k1(
    const float* __restrict__ s, const float* __restrict__ ctx,
    const float* __restrict__ Wl, const float* __restrict__ bl,
    unsigned short* __restrict__ ws16, float* __restrict__ cws)
{
    // Abuf u16[2wm][16ks][64l][8] = 32KB @0 ; Bbuf u16[16ks][64l][8] = 16KB
    // @32768 ; red f32[3][32][20] @49152 (7.7KB)
    __shared__ __align__(16) unsigned char smem[56832];

    const int bid = blockIdx.x;
    const int t = threadIdx.x;
    const int w = t >> 6, l = t & 63;
    const int lk = l & 15, kq = l >> 4;

    if (bid < 256) {
        // ---------------- GEMM2: rows [32mt,32mt+32), cols [16nt,16nt+16)
        const int mt = bid >> 6, nt = bid & 63;
        const int col = nt * 16 + lk;
        unsigned short* Abuf = reinterpret_cast<unsigned short*>(smem);
        unsigned short* Bbuf = reinterpret_cast<unsigned short*>(smem + 32768);
        float* red = reinterpret_cast<float*>(smem + 49152);

        // stage B frags: each wave 2 ks (scalar gather, coalesced over lk)
        #pragma unroll 2
        for (int i = 0; i < 2; ++i) {
            const int ks = w * 2 + i;
            const int kb = ks * 32;
            bf16x8 fr;
            #pragma unroll
            for (int jj = 0; jj < 4; ++jj)
                fr[jj] = (__bf16)Wl[(size_t)(kb + 4 * kq + jj) * 1024 + col];
            #pragma unroll
            for (int jj = 0; jj < 4; ++jj)
                fr[4 + jj] = (__bf16)Wl[(size_t)(kb + 16 + 4 * kq + jj) * 1024 + col];
            *reinterpret_cast<uint4*>(&Bbuf[(ks * 64 + l) * 8]) = __builtin_bit_cast(uint4, fr);
        }

        // stage A coalesced -> fragment-layout LDS
        {
            const int r = t >> 4;                    // 0..31
            const int wmA = r >> 4, lkA = r & 15;
            const float* src = s + (size_t)(mt * 32 + r) * 1536;
            #pragma unroll 8
            for (int rep = 0; rep < 8; ++rep) {
                const int q = (t & 15) + 16 * rep;   // f32-quad 0..127
                float4 v = *reinterpret_cast<const float4*>(src + 4 * q);
                const int ksA = q >> 3, kqA = q & 3, half = (q >> 2) & 1;
                const int off = ((wmA * 16 + ksA) * 64 + kqA * 16 + lkA) * 8 + half * 4;
                *reinterpret_cast<uint2*>(&Abuf[off]) = cvt4(v);
            }
        }
        __syncthreads();

        // compute: wave = (wm, wk); 4 ks each; pure LDS->MFMA
        const int wm = w & 1, wk = w >> 1;
        f32x4 acc0 = (f32x4){0.f, 0.f, 0.f, 0.f};
        f32x4 acc1 = (f32x4){0.f, 0.f, 0.f, 0.f};
        #pragma unroll 4
        for (int i = 0; i < 4; ++i) {
            const int ks = wk * 4 + i;
            uint4 av = *reinterpret_cast<const uint4*>(&Abuf[((wm * 16 + ks) * 64 + l) * 8]);
            uint4 bv = *reinterpret_cast<const uint4*>(&Bbuf[(ks * 64 + l) * 8]);
            if (i & 1) acc1 = MFMA(av, bv, acc1);
            else       acc0 = MFMA(av, bv, acc0);
        }
        f32x4 sum = acc0 + acc1;

        // 4-way K reduce (R6-validated pattern)
        if (wk > 0) {
            #pragma unroll
            for (int r = 0; r < 4; ++r)
                red[((wk - 1) * 32 + wm * 16 + 4 * kq + r) * 20 + lk] = sum[r];
        }
        __syncthreads();
        if (wk == 0) {
            const float bias = bl[col];
            #pragma unroll
            for (int r = 0; r < 4; ++r) {
                const int m = wm * 16 + 4 * kq + r;
                float v = sum[r] + red[m * 20 + lk] + red[(32 + m) * 20 + lk]
                        + red[(64 + m) * 20 + lk] + bias;
                cws[(size_t)(mt * 32 + m) * 1024 + col] = v;
            }
        }
    } else {
        // ---------------- Apack: [a|ctx] -> bf16 frags (R4-validated)
        const int base = (bid - 256) * 512 + t;
        #pragma unroll 2
        for (int rep = 0; rep < 2; ++rep) {
            const int idx = base + rep * 8192;
            const int mt = idx >> 11, ks = (idx >> 6) & 31, l2 = idx & 63;
            const int lk2 = l2 & 15, kq2 = l2 >> 4;
            const int row = 16 * mt + lk2, kb = 32 * ks;
            float4 v0, v1;
            if (ks < 16) {
                v0 = *reinterpret_cast<const float4*>(s + (size_t)row * 1536 + kb + 4 * kq2);
                v1 = *reinterpret_cast<const float4*>(s + (size_t)row * 1536 + kb + 16 + 4 * kq2);
            } else {
                v0 = *reinterpret_cast<const float4*>(ctx + (size_t)row * 512 + (kb - 512) + 4 * kq2);
                v1 = *reinterpret_cast<const float4*>(ctx + (size_t)row * 512 + (kb - 512) + 16 + 4 * kq2);
            }
            bf16x8 fr = pack2(v0, v1);
            *reinterpret_cast<uint4*>(ws16 + (size_t)idx * 8) = __builtin_bit_cast(uint4, fr);
        }
    }
}

// ---------------------------------------------------------------------------
// k2: 512 blocks x 512 threads.  [0,256): dz ; [256,512): GEMM1
// ---------------------------------------------------------------------------
__global__ __launch_bounds__(512) void k2(
    const float* __restrict__ s,
    const float* __restrict__ Wa, const float* __restrict__ Wc,
    const float* __restrict__ ba,
    const unsigned short* __restrict__ apack, const float* __restrict__ cws,
    float* __restrict__ out)
{
    __shared__ __align__(16) unsigned char smem[37888];

    const int bid = blockIdx.x;
    const int t = threadIdx.x;

    if (bid < 256) {
        // ---------------- dz (R3-validated body)
        float* zdup = reinterpret_cast<float*>(smem);             // 2064 f
        float* part = reinterpret_cast<float*>(smem + 8448);      // 8*512 f
        const int b = bid >> 1;
        const int ih = bid & 1;
        if (t < 256) {
            float4 v = reinterpret_cast<const float4*>(s + (size_t)b * 1536 + 512)[t];
            reinterpret_cast<float4*>(zdup)[t] = v;
            reinterpret_cast<float4*>(zdup)[256 + t] = v;
        }
        __syncthreads();
        const int g = t & 63;
        const int kq = __builtin_amdgcn_readfirstlane(t >> 6);
        const float4* c4 = reinterpret_cast<const float4*>(cws + (size_t)b * 1024 + kq * 128);
        const int I0 = ih * 512;
        const float4* z4 = reinterpret_cast<const float4*>(zdup);
        const int baseA = (I0 >> 2) + g + kq * 32;
        const int baseB = baseA + 64;
        float4 a0 = z4[baseA], a1 = z4[baseA + 1];
        float4 b0 = z4[baseB], b1 = z4[baseB + 1];
        float accA[4] = {0.f, 0.f, 0.f, 0.f}, accB[4] = {0.f, 0.f, 0.f, 0.f};
        #pragma unroll 4
        for (int m = 0; m < 32; ++m) {
            float4 cv = c4[m];
            float4 a2 = z4[baseA + m + 2];
            float4 b2 = z4[baseB + m + 2];
            accA[0] = fmaf(cv.x, a0.x, accA[0]); accA[0] = fmaf(cv.y, a0.y, accA[0]);
            accA[0] = fmaf(cv.z, a0.z, accA[0]); accA[0] = fmaf(cv.w, a0.w, accA[0]);
            accA[1] = fmaf(cv.x, a0.y, accA[1]); accA[1] = fmaf(cv.y, a0.z, accA[1]);
            accA[1] = fmaf(cv.z, a0.w, accA[1]); accA[1] = fmaf(cv.w, a1.x, accA[1]);
            accA[2] = fmaf(cv.x, a0.z, accA[2]); accA[2] = fmaf(cv.y, a0.w, accA[2]);
            accA[2] = fmaf(cv.z, a1.x, accA[2]); accA[2] = fmaf(cv.w, a1.y, accA[2]);
            accA[3] = fmaf(cv.x, a0.w, accA[3]); accA[3] = fmaf(cv.y, a1.x, accA[3]);
            accA[3] = fmaf(cv.z, a1.y, accA[3]); accA[3] = fmaf(cv.w, a1.z, accA[3]);
            accB[0] = fmaf(cv.x, b0.x, accB[0]); accB[0] = fmaf(cv.y, b0.y, accB[0]);
            accB[0] = fmaf(cv.z, b0.z, accB[0]); accB[0] = fmaf(cv.w, b0.w, accB[0]);
            accB[1] = fmaf(cv.x, b0.y, accB[1]); accB[1] = fmaf(cv.y, b0.z, accB[1]);
            accB[1] = fmaf(cv.z, b0.w, accB[1]); accB[1] = fmaf(cv.w, b1.x, accB[1]);
            accB[2] = fmaf(cv.x, b0.z, accB[2]); accB[2] = fmaf(cv.y, b0.w, accB[2]);
            accB[2] = fmaf(cv.z, b1.x, accB[2]); accB[2] = fmaf(cv.w, b1.y, accB[2]);
            accB[3] = fmaf(cv.x, b0.w, accB[3]); accB[3] = fmaf(cv.y, b1.x, accB[3]);
            accB[3] = fmaf(cv.z, b1.y, accB[3]); accB[3] = fmaf(cv.w, b1.z, accB[3]);
            a0 = a1; a1 = a2; b0 = b1; b1 = b2;
        }
        *reinterpret_cast<float4*>(&part[kq * 512 + 4 * g]) =
            make_float4(accA[0], accA[1], accA[2], accA[3]);
        *reinterpret_cast<float4*>(&part[kq * 512 + 256 + 4 * g]) =
            make_float4(accB[0], accB[1], accB[2], accB[3]);
        __syncthreads();
        float sumz = 0.f;
        #pragma unroll
        for (int q = 0; q < 8; ++q) sumz += part[q * 512 + t];
        out[(size_t)b * 1536 + 512 + I0 + t] = sumz;
    } else {
        // ---------------- GEMM1: rows [16mt,16mt+16), cols [16nt,16nt+16)
        unsigned short* Bg = reinterpret_cast<unsigned short*>(smem);   // 32KB
        float* red = reinterpret_cast<float*>(smem + 32768);            // [4][16*17]
        const int j = bid - 256;
        const int mt = j >> 5, nt = j & 31;
        const int w = t >> 6, l = t & 63;
        const int lk = l & 15, kq = l >> 4;
        const int col = nt * 16 + lk;

        // stage B frags: each wave 4 ks (R6-validated gather)
        #pragma unroll 4
        for (int i = 0; i < 4; ++i) {
            const int ks = w * 4 + i;
            const int kb = ks * 32;
            const float* wb; int krel;
            if (ks < 16) { wb = Wa; krel = kb; } else { wb = Wc; krel = kb - 512; }
            bf16x8 fr;
            #pragma unroll
            for (int jj = 0; jj < 4; ++jj)
                fr[jj] = (__bf16)wb[(size_t)(krel + 4 * kq + jj) * 512 + col];
            #pragma unroll
            for (int jj = 0; jj < 4; ++jj)
                fr[4 + jj] = (__bf16)wb[(size_t)(krel + 16 + 4 * kq + jj) * 512 + col];
            *reinterpret_cast<uint4*>(&Bg[(ks * 64 + l) * 8]) = __builtin_bit_cast(uint4, fr);
        }
        __syncthreads();

        // compute: wave w = K-chunk (4 ks); A streamed from Apack
        f32x4 acc0 = (f32x4){0.f, 0.f, 0.f, 0.f};
        f32x4 acc1 = (f32x4){0.f, 0.f, 0.f, 0.f};
        #pragma unroll 4
        for (int i = 0; i < 4; ++i) {
            const int ks = w * 4 + i;
            uint4 av = *reinterpret_cast<const uint4*>(apack + ((size_t)(mt * 32 + ks) * 64 + l) * 8);
            uint4 bv = *reinterpret_cast<const uint4*>(&Bg[(ks * 64 + l) * 8]);
            if (i & 1) acc1 = MFMA(av, bv, acc1);
            else       acc0 = MFMA(av, bv, acc0);
        }
        f32x4 sum = acc0 + acc1;

        // 8-way K reduce (R3 k_mm pattern)
        if (w < 4) {
            #pragma unroll
            for (int r = 0; r < 4; ++r)
                red[w * 272 + (kq * 4 + r) * 17 + lk] = sum[r];
        }
        __syncthreads();
        if (w >= 4) {
            #pragma unroll
            for (int r = 0; r < 4; ++r)
                red[(w - 4) * 272 + (kq * 4 + r) * 17 + lk] += sum[r];
        }
        __syncthreads();
        if (t < 256) {
            const int m = t >> 4, n = t & 15;
            const int o = m * 17 + n;
            const int colo = nt * 16 + n;
            float v = red[o] + red[272 + o] + red[544 + o] + red[816 + o] + ba[colo];
            out[(size_t)(mt * 16 + m) * 1536 + colo] = tanhf(v);
        }
    }
}

extern "C" void kernel_launch(void* const* d_in, const int* in_sizes, int n_in,
                              void* d_out, int out_size, void* d_ws, size_t ws_size,
                              hipStream_t stream) {
    // inputs: 0=t, 1=s, 2=context, 3=Wa, 4=Wc, 5=ba, 6=Wl, 7=bl
    const float* s   = (const float*)d_in[1];
    const float* ctx = (const float*)d_in[2];
    const float* Wa  = (const float*)d_in[3];
    const float* Wc  = (const float*)d_in[4];
    const float* ba  = (const float*)d_in[5];
    const float* Wl  = (const float*)d_in[6];
    const float* bl  = (const float*)d_in[7];
    float* out = (float*)d_out;

    unsigned short* ws16 = (unsigned short*)d_ws;
    float* cws = (float*)((char*)d_ws + C_OFF_BYTES);

    k1<<<272, 512, 0, stream>>>(s, ctx, Wl, bl, ws16, cws);
    k2<<<512, 512, 0, stream>>>(s, Wa, Wc, ba, ws16, cws, out);
}

// Round 9
// 14.576 us; speedup vs baseline: 4.0607x; 1.0951x over previous
//
#include <hip/hip_runtime.h>
#include <math.h>

// B=128, N=512, D=1024, C=512
// s: (128,1536) f32, a=s[:,:512], z=s[:,512:]; out: (128,1536) f32 = [da | dz]
// GEMM1: da = tanh([a|ctx](128x1024) @ [Wa;Wc](1024x512) + ba)
// GEMM2: c  = a(128x512) @ Wl(512x1024) + bl          -> ws
// dz[b,i] = sum_k c[b,k] * z[b,(i+k)%1024]
//
// k1 (272 blocks): [0,256) GEMM2 (A coalesced->LDS frags, B gather, 2Mx4K
//     waves, 4-way K reduce, c->ws); [256,272) Apack.     [R8-validated]
// k2 (512 blocks): [0,256) dz-v2: packed f32x2 FMA (v_pk_fma_f32) with dual
//     LDS windows (zdup + one-element-shifted zs) -> all float2 accesses
//     aligned; 8 consecutive outputs/thread, K-split 8 + LDS reduce.
//     [256,512) GEMM1 (A from Apack, B gather LDS, 8-way K reduce, tanh).
//     [GEMM code R8-validated; dz restructured this round]
//
// ws: Apack @0 (256 KB) ; c @262144 (512 KB)
// Fragment k-slot bijection sigma(kq,j): j<4 -> 4kq+j ; j>=4 -> 16+4kq+(j-4),
// applied identically to A and B (validated rounds 2-8).

typedef float f32x4 __attribute__((ext_vector_type(4)));
typedef float f32x2 __attribute__((ext_vector_type(2)));
typedef float f32x4v __attribute__((ext_vector_type(4)));
typedef __bf16 bf16x8 __attribute__((ext_vector_type(8)));
typedef __bf16 bf16x4 __attribute__((ext_vector_type(4)));

#define C_OFF_BYTES 262144

__device__ __forceinline__ bf16x8 pack2(float4 v0, float4 v1) {
    bf16x8 r;
    r[0] = (__bf16)v0.x; r[1] = (__bf16)v0.y; r[2] = (__bf16)v0.z; r[3] = (__bf16)v0.w;
    r[4] = (__bf16)v1.x; r[5] = (__bf16)v1.y; r[6] = (__bf16)v1.z; r[7] = (__bf16)v1.w;
    return r;
}

__device__ __forceinline__ uint2 cvt4(float4 v) {
    bf16x4 r;
    r[0] = (__bf16)v.x; r[1] = (__bf16)v.y; r[2] = (__bf16)v.z; r[3] = (__bf16)v.w;
    return __builtin_bit_cast(uint2, r);
}

__device__ __forceinline__ f32x4 MFMA(uint4 a, uint4 b, f32x4 c) {
    return __builtin_amdgcn_mfma_f32_16x16x32_bf16(
        __builtin_bit_cast(bf16x8, a), __builtin_bit_cast(bf16x8, b), c, 0, 0, 0);
}

// ---------------------------------------------------------------------------
// k1: 272 blocks x 512 threads.  [0,256): GEMM2 ; [256,272): Apack
// ---------------------------------------------------------------------------
__global__ __launch_bounds__(512) void k1(
    const float* __restrict__ s, const float* __restrict__ ctx,
    const float* __restrict__ Wl, const float* __restrict__ bl,
    unsigned short* __restrict__ ws16, float* __restrict__ cws)
{
    __shared__ __align__(16) unsigned char smem[56832];

    const int bid = blockIdx.x;
    const int t = threadIdx.x;
    const int w = t >> 6, l = t & 63;
    const int lk = l & 15, kq = l >> 4;

    if (bid < 256) {
        // ---------------- GEMM2: rows [32mt,32mt+32), cols [16nt,16nt+16)
        const int mt = bid >> 6, nt = bid & 63;
        const int col = nt * 16 + lk;
        unsigned short* Abuf = reinterpret_cast<unsigned short*>(smem);
        unsigned short* Bbuf = reinterpret_cast<unsigned short*>(smem + 32768);
        float* red = reinterpret_cast<float*>(smem + 49152);

        #pragma unroll 2
        for (int i = 0; i < 2; ++i) {
            const int ks = w * 2 + i;
            const int kb = ks * 32;
            bf16x8 fr;
            #pragma unroll
            for (int jj = 0; jj < 4; ++jj)
                fr[jj] = (__bf16)Wl[(size_t)(kb + 4 * kq + jj) * 1024 + col];
            #pragma unroll
            for (int jj = 0; jj < 4; ++jj)
                fr[4 + jj] = (__bf16)Wl[(size_t)(kb + 16 + 4 * kq + jj) * 1024 + col];
            *reinterpret_cast<uint4*>(&Bbuf[(ks * 64 + l) * 8]) = __builtin_bit_cast(uint4, fr);
        }

        {
            const int r = t >> 4;
            const int wmA = r >> 4, lkA = r & 15;
            const float* src = s + (size_t)(mt * 32 + r) * 1536;
            #pragma unroll 8
            for (int rep = 0; rep < 8; ++rep) {
                const int q = (t & 15) + 16 * rep;
                float4 v = *reinterpret_cast<const float4*>(src + 4 * q);
                const int ksA = q >> 3, kqA = q & 3, half = (q >> 2) & 1;
                const int off = ((wmA * 16 + ksA) * 64 + kqA * 16 + lkA) * 8 + half * 4;
                *reinterpret_cast<uint2*>(&Abuf[off]) = cvt4(v);
            }
        }
        __syncthreads();

        const int wm = w & 1, wk = w >> 1;
        f32x4 acc0 = (f32x4){0.f, 0.f, 0.f, 0.f};
        f32x4 acc1 = (f32x4){0.f, 0.f, 0.f, 0.f};
        #pragma unroll 4
        for (int i = 0; i < 4; ++i) {
            const int ks = wk * 4 + i;
            uint4 av = *reinterpret_cast<const uint4*>(&Abuf[((wm * 16 + ks) * 64 + l) * 8]);
            uint4 bv = *reinterpret_cast<const uint4*>(&Bbuf[(ks * 64 + l) * 8]);
            if (i & 1) acc1 = MFMA(av, bv, acc1);
            else       acc0 = MFMA(av, bv, acc0);
        }
        f32x4 sum = acc0 + acc1;

        if (wk > 0) {
            #pragma unroll
            for (int r = 0; r < 4; ++r)
                red[((wk - 1) * 32 + wm * 16 + 4 * kq + r) * 20 + lk] = sum[r];
        }
        __syncthreads();
        if (wk == 0) {
            const float bias = bl[col];
            #pragma unroll
            for (int r = 0; r < 4; ++r) {
                const int m = wm * 16 + 4 * kq + r;
                float v = sum[r] + red[m * 20 + lk] + red[(32 + m) * 20 + lk]
                        + red[(64 + m) * 20 + lk] + bias;
                cws[(size_t)(mt * 32 + m) * 1024 + col] = v;
            }
        }
    } else {
        // ---------------- Apack
        const int base = (bid - 256) * 512 + t;
        #pragma unroll 2
        for (int rep = 0; rep < 2; ++rep) {
            const int idx = base + rep * 8192;
            const int mt = idx >> 11, ks = (idx >> 6) & 31, l2 = idx & 63;
            const int lk2 = l2 & 15, kq2 = l2 >> 4;
            const int row = 16 * mt + lk2, kb = 32 * ks;
            float4 v0, v1;
            if (ks < 16) {
                v0 = *reinterpret_cast<const float4*>(s + (size_t)row * 1536 + kb + 4 * kq2);
                v1 = *reinterpret_cast<const float4*>(s + (size_t)row * 1536 + kb + 16 + 4 * kq2);
            } else {
                v0 = *reinterpret_cast<const float4*>(ctx + (size_t)row * 512 + (kb - 512) + 4 * kq2);
                v1 = *reinterpret_cast<const float4*>(ctx + (size_t)row * 512 + (kb - 512) + 16 + 4 * kq2);
            }
            bf16x8 fr = pack2(v0, v1);
            *reinterpret_cast<uint4*>(ws16 + (size_t)idx * 8) = __builtin_bit_cast(uint4, fr);
        }
    }
}

// ---------------------------------------------------------------------------
// k2: 512 blocks x 512 threads.  [0,256): dz-v2 (packed f32) ; [256,512): GEMM1
// ---------------------------------------------------------------------------
__global__ __launch_bounds__(512) void k2(
    const float* __restrict__ s,
    const float* __restrict__ Wa, const float* __restrict__ Wc,
    const float* __restrict__ ba,
    const unsigned short* __restrict__ apack, const float* __restrict__ cws,
    float* __restrict__ out)
{
    __shared__ __align__(16) unsigned char smem[37888];

    const int bid = blockIdx.x;
    const int t = threadIdx.x;

    if (bid < 256) {
        // ---------------- dz-v2: packed f32x2 FMA, dual shifted windows
        float* zdup = reinterpret_cast<float*>(smem);             // 2064 f @0
        float* zsh  = reinterpret_cast<float*>(smem + 8256);      // 2052 f
        float* part = reinterpret_cast<float*>(smem + 16464);     // 4096 f
        const int b = bid >> 1;
        const int I0 = (bid & 1) * 512;
        const float* zrow = s + (size_t)b * 1536 + 512;

        if (t < 256) {
            float4 v = reinterpret_cast<const float4*>(zrow)[t];
            reinterpret_cast<float4*>(zdup)[t] = v;
            reinterpret_cast<float4*>(zdup)[256 + t] = v;
        } else if (t == 256) {
            reinterpret_cast<float4*>(zdup)[512] = reinterpret_cast<const float4*>(zrow)[0];
        }
        __syncthreads();
        {
            f32x4v v0 = reinterpret_cast<const f32x4v*>(zdup)[t];
            f32x4v v1 = reinterpret_cast<const f32x4v*>(zdup)[t + 1];
            f32x4v r = {v0.y, v0.z, v0.w, v1.x};
            reinterpret_cast<f32x4v*>(zsh)[t] = r;
        }
        __syncthreads();

        const int g = t & 63;
        const int kq = __builtin_amdgcn_readfirstlane(t >> 6);
        const int i0 = 8 * g;                  // local output base (8 outputs)
        const int koff = kq * 128;             // K-chunk
        const int eb = (I0 + i0 + koff) >> 2;  // float4 window base (mult of 4)

        const f32x4v* zE = reinterpret_cast<const f32x4v*>(zdup);
        const f32x4v* zO = reinterpret_cast<const f32x4v*>(zsh);
        const f32x4v* c4 = reinterpret_cast<const f32x4v*>(cws + (size_t)b * 1024 + koff);

        f32x4v e0 = zE[eb], e1 = zE[eb + 1];
        f32x4v o0 = zO[eb], o1 = zO[eb + 1];
        f32x2 acc[8];
        #pragma unroll
        for (int q = 0; q < 8; ++q) acc[q] = (f32x2){0.f, 0.f};

        #pragma unroll 8
        for (int p2 = 0; p2 < 32; ++p2) {
            f32x4v cf = c4[p2];
            f32x4v e2 = zE[eb + p2 + 2];
            f32x4v o2 = zO[eb + p2 + 2];
            f32x2 cA = cf.lo, cB = cf.hi;
            // even k-pair (m2 = 2*p2)
            acc[0] = __builtin_elementwise_fma(cA, e0.lo, acc[0]);
            acc[1] = __builtin_elementwise_fma(cA, o0.lo, acc[1]);
            acc[2] = __builtin_elementwise_fma(cA, e0.hi, acc[2]);
            acc[3] = __builtin_elementwise_fma(cA, o0.hi, acc[3]);
            acc[4] = __builtin_elementwise_fma(cA, e1.lo, acc[4]);
            acc[5] = __builtin_elementwise_fma(cA, o1.lo, acc[5]);
            acc[6] = __builtin_elementwise_fma(cA, e1.hi, acc[6]);
            acc[7] = __builtin_elementwise_fma(cA, o1.hi, acc[7]);
            // odd k-pair (m2 = 2*p2+1): window shifted one float2
            acc[0] = __builtin_elementwise_fma(cB, e0.hi, acc[0]);
            acc[1] = __builtin_elementwise_fma(cB, o0.hi, acc[1]);
            acc[2] = __builtin_elementwise_fma(cB, e1.lo, acc[2]);
            acc[3] = __builtin_elementwise_fma(cB, o1.lo, acc[3]);
            acc[4] = __builtin_elementwise_fma(cB, e1.hi, acc[4]);
            acc[5] = __builtin_elementwise_fma(cB, o1.hi, acc[5]);
            acc[6] = __builtin_elementwise_fma(cB, e2.lo, acc[6]);
            acc[7] = __builtin_elementwise_fma(cB, o2.lo, acc[7]);
            e0 = e1; e1 = e2; o0 = o1; o1 = o2;
        }

        float4 r0, r1;
        r0.x = acc[0].x + acc[0].y; r0.y = acc[1].x + acc[1].y;
        r0.z = acc[2].x + acc[2].y; r0.w = acc[3].x + acc[3].y;
        r1.x = acc[4].x + acc[4].y; r1.y = acc[5].x + acc[5].y;
        r1.z = acc[6].x + acc[6].y; r1.w = acc[7].x + acc[7].y;
        reinterpret_cast<float4*>(&part[kq * 512 + i0])[0] = r0;
        reinterpret_cast<float4*>(&part[kq * 512 + i0])[1] = r1;
        __syncthreads();
        float sumz = 0.f;
        #pragma unroll
        for (int q = 0; q < 8; ++q) sumz += part[q * 512 + t];
        out[(size_t)b * 1536 + 512 + I0 + t] = sumz;
    } else {
        // ---------------- GEMM1 (R8-validated)
        unsigned short* Bg = reinterpret_cast<unsigned short*>(smem);   // 32KB
        float* red = reinterpret_cast<float*>(smem + 32768);
        const int j = bid - 256;
        const int mt = j >> 5, nt = j & 31;
        const int w = t >> 6, l = t & 63;
        const int lk = l & 15, kq = l >> 4;
        const int col = nt * 16 + lk;

        #pragma unroll 4
        for (int i = 0; i < 4; ++i) {
            const int ks = w * 4 + i;
            const int kb = ks * 32;
            const float* wb; int krel;
            if (ks < 16) { wb = Wa; krel = kb; } else { wb = Wc; krel = kb - 512; }
            bf16x8 fr;
            #pragma unroll
            for (int jj = 0; jj < 4; ++jj)
                fr[jj] = (__bf16)wb[(size_t)(krel + 4 * kq + jj) * 512 + col];
            #pragma unroll
            for (int jj = 0; jj < 4; ++jj)
                fr[4 + jj] = (__bf16)wb[(size_t)(krel + 16 + 4 * kq + jj) * 512 + col];
            *reinterpret_cast<uint4*>(&Bg[(ks * 64 + l) * 8]) = __builtin_bit_cast(uint4, fr);
        }
        __syncthreads();

        f32x4 acc0 = (f32x4){0.f, 0.f, 0.f, 0.f};
        f32x4 acc1 = (f32x4){0.f, 0.f, 0.f, 0.f};
        #pragma unroll 4
        for (int i = 0; i < 4; ++i) {
            const int ks = w * 4 + i;
            uint4 av = *reinterpret_cast<const uint4*>(apack + ((size_t)(mt * 32 + ks) * 64 + l) * 8);
            uint4 bv = *reinterpret_cast<const uint4*>(&Bg[(ks * 64 + l) * 8]);
            if (i & 1) acc1 = MFMA(av, bv, acc1);
            else       acc0 = MFMA(av, bv, acc0);
        }
        f32x4 sum = acc0 + acc1;

        if (w < 4) {
            #pragma unroll
            for (int r = 0; r < 4; ++r)
                red[w * 272 + (kq * 4 + r) * 17 + lk] = sum[r];
        }
        __syncthreads();
        if (w >= 4) {
            #pragma unroll
            for (int r = 0; r < 4; ++r)
                red[(w - 4) * 272 + (kq * 4 + r) * 17 + lk] += sum[r];
        }
        __syncthreads();
        if (t < 256) {
            const int m = t >> 4, n = t & 15;
            const int o = m * 17 + n;
            const int colo = nt * 16 + n;
            float v = red[o] + red[272 + o] + red[544 + o] + red[816 + o] + ba[colo];
            out[(size_t)(mt * 16 + m) * 1536 + colo] = tanhf(v);
        }
    }
}

extern "C" void kernel_launch(void* const* d_in, const int* in_sizes, int n_in,
                              void* d_out, int out_size, void* d_ws, size_t ws_size,
                              hipStream_t stream) {
    // inputs: 0=t, 1=s, 2=context, 3=Wa, 4=Wc, 5=ba, 6=Wl, 7=bl
    const float* s   = (const float*)d_in[1];
    const float* ctx = (const float*)d_in[2];
    const float* Wa  = (const float*)d_in[3];
    const float* Wc  = (const float*)d_in[4];
    const float* ba  = (const float*)d_in[5];
    const float* Wl  = (const float*)d_in[6];
    const float* bl  = (const float*)d_in[7];
    float* out = (float*)d_out;

    unsigned short* ws16 = (unsigned short*)d_ws;
    float* cws = (float*)((char*)d_ws + C_OFF_BYTES);

    k1<<<272, 512, 0, stream>>>(s, ctx, Wl, bl, ws16, cws);
    k2<<<512, 512, 0, stream>>>(s, Wa, Wc, ba, ws16, cws, out);
}